// Round 1
// baseline (926.689 us; speedup 1.0000x reference)
//
#include <hip/hip_runtime.h>

typedef unsigned int u32;
typedef unsigned long long u64;

#define TSEQ 2048

// monotone fp32 -> u32 map (order-preserving)
__device__ __forceinline__ u32 f2sort(float f) {
  u32 u = __float_as_uint(f);
  return u ^ ((u32)((int)u >> 31) | 0x80000000u);
}
__device__ __forceinline__ float sort2f(u32 u) {
  u ^= (u & 0x80000000u) ? 0x80000000u : 0xFFFFFFFFu;
  return __uint_as_float(u);
}

// ---------------------------------------------------------------------------
// Generic fp32 NT GEMM: C[m,n] = sum_k A[m,k] * B[n,k]  (+ optional bias[n])
// dots mode: blockIdx.z = h*2+p selects Q column slice / keys slice / D slab.
// 64x64 tile, 256 threads, 4x4 micro-tile, BK=16.
// ---------------------------------------------------------------------------
__global__ __launch_bounds__(256) void gemm_nt(
    const float* __restrict__ A, int lda,
    const float* __restrict__ B, int ldb,
    const float* __restrict__ bias,
    float* __restrict__ C, int ldc, int K, int dots) {
  if (dots) {
    int z = blockIdx.z;
    int h = z >> 1, p = z & 1;
    A += p * 1024 + h * 128;                 // Q column offset (lda=2048)
    B += (size_t)(h * 512 + p) * 128;        // keys[h, 0, p, 0], row stride 256
    C += (size_t)z * 4096 * 256;             // D slab per (h,p)
  }
  __shared__ float As[16][64];   // [k][m]
  __shared__ float Bs[16][64];   // [k][n]
  const int tid = threadIdx.x;
  const int m0 = blockIdx.y << 6, n0 = blockIdx.x << 6;
  const int lrow = tid >> 2, lkq = tid & 3;  // staging: 64 rows x 4 k-quads
  const int tx = tid & 15, ty = tid >> 4;    // compute: 16x16 threads
  const float* Ap = A + (size_t)(m0 + lrow) * lda + lkq * 4;
  const float* Bp = B + (size_t)(n0 + lrow) * ldb + lkq * 4;
  float acc[4][4];
#pragma unroll
  for (int i = 0; i < 4; i++)
#pragma unroll
    for (int j = 0; j < 4; j++) acc[i][j] = 0.f;
  for (int k0 = 0; k0 < K; k0 += 16) {
    float4 av = *(const float4*)(Ap + k0);
    float4 bv = *(const float4*)(Bp + k0);
    __syncthreads();   // previous tile fully consumed
    As[lkq * 4 + 0][lrow] = av.x; As[lkq * 4 + 1][lrow] = av.y;
    As[lkq * 4 + 2][lrow] = av.z; As[lkq * 4 + 3][lrow] = av.w;
    Bs[lkq * 4 + 0][lrow] = bv.x; Bs[lkq * 4 + 1][lrow] = bv.y;
    Bs[lkq * 4 + 2][lrow] = bv.z; Bs[lkq * 4 + 3][lrow] = bv.w;
    __syncthreads();
#pragma unroll
    for (int kk = 0; kk < 16; kk++) {
      float4 a4 = *(const float4*)&As[kk][ty << 2];   // b128, conflict-free
      float4 b4 = *(const float4*)&Bs[kk][tx << 2];   // b128, 2-way (free)
      float ar[4] = {a4.x, a4.y, a4.z, a4.w};
      float br[4] = {b4.x, b4.y, b4.z, b4.w};
#pragma unroll
      for (int i = 0; i < 4; i++)
#pragma unroll
        for (int j = 0; j < 4; j++) acc[i][j] += ar[i] * br[j];
    }
  }
  float4 bb = make_float4(0.f, 0.f, 0.f, 0.f);
  if (bias) bb = *(const float4*)(bias + n0 + (tx << 2));
#pragma unroll
  for (int i = 0; i < 4; i++) {
    float4 o = make_float4(acc[i][0] + bb.x, acc[i][1] + bb.y,
                           acc[i][2] + bb.z, acc[i][3] + bb.w);
    *(float4*)(C + (size_t)(m0 + (ty << 2) + i) * ldc + n0 + (tx << 2)) = o;
  }
}

// ---------------------------------------------------------------------------
// Stage-1 top-32 of 256 per row. 16 lanes/row, 4 rows/wave, 16 rows/block.
// Packed key: sortable(score) with low 8 bits = register slot s; element
// index n = lane + 16*s. Output sorted descending (required by stage 2).
// ---------------------------------------------------------------------------
__global__ __launch_bounds__(256) void topk1(
    const float* __restrict__ D, float* __restrict__ s1score,
    int* __restrict__ s1idx) {
  const int tid = threadIdx.x;
  const int rloc = tid >> 4;
  const int l = tid & 15;
  const int wid = blockIdx.x * 16 + rloc;   // 0..65535 = (hp, b, t)
  const float* row = D + (size_t)wid * 256;
  u32 key[16];
#pragma unroll
  for (int s = 0; s < 16; s++) {
    float v = row[l + 16 * s];
    key[s] = (f2sort(v) & ~0xFFu) | (u32)s;
  }
  const int wl = tid & 63;
  const int grp = wl & 48;                  // group base lane in wave
  float myw0 = 0.f, myw1 = 0.f;
  int myi0 = 0, myi1 = 0;
  for (int it = 0; it < 32; it++) {
    u32 lm = key[0];
#pragma unroll
    for (int s = 1; s < 16; s++) lm = key[s] > lm ? key[s] : lm;
    u32 gm = lm;
#pragma unroll
    for (int d = 1; d < 16; d <<= 1) {
      u32 o = (u32)__shfl_xor((int)gm, d);
      gm = o > gm ? o : gm;
    }
    u64 mask = __ballot(lm == gm);
    int owner = __ffsll((u64)((mask >> grp) & 0xFFFFull)) - 1;  // lane in grp
    int swin = (int)(gm & 0xFFu);
    int idx = swin * 16 + owner;            // element index n
    float score = sort2f(gm & ~0xFFu);
    bool isown = (l == owner);
#pragma unroll
    for (int s = 0; s < 16; s++)
      key[s] = (isown && s == swin) ? 0u : key[s];
    if (l == (it & 15)) {
      if (it < 16) { myw0 = score; myi0 = idx; }
      else         { myw1 = score; myi1 = idx; }
    }
  }
  // wid = hp*4096 + b*2048 + t  ->  output row ((b*8+h)*2048+t)*2+p
  int hp = wid >> 12, r = wid & 4095;
  int h = hp >> 1, p = hp & 1;
  int b = r >> 11, t = r & 2047;
  size_t orow = ((((size_t)(b * 8 + h)) * TSEQ + t) * 2 + p) * 32;
  s1score[orow + l] = myw0;
  s1score[orow + l + 16] = myw1;
  s1idx[orow + l] = myi0;
  s1idx[orow + l + 16] = myi1;
}

// ---------------------------------------------------------------------------
// Stage-2: per output row (b,h,t): combine s0 (from t>>1) and s1 (from
// (t>>1)+1024), top-32 of the 32x32 sum grid via the dominance frontier
// ((i+1)(j+1)<=32 -> 119 candidates), softmax, gather values, weighted sum.
// 16 lanes/row, 16 rows/block.
// ---------------------------------------------------------------------------
__global__ __launch_bounds__(256) void topk2_gather(
    const float* __restrict__ s1s, const int* __restrict__ s1i,
    const float* __restrict__ values, float* __restrict__ headout) {
  __shared__ unsigned short cand[128];      // (i<<5)|j, 0xFFFF = pad
  __shared__ float s0sh[16][32];
  __shared__ float s1sh[16][32];
  __shared__ int i0sh[16][32];
  __shared__ int i1sh[16][32];
  const int tid = threadIdx.x;
  if (tid < 128) {
    int c = tid;
    unsigned short enc = 0xFFFF;
    if (c < 119) {
      int rem = c, i = 0;
      for (i = 0; i < 32; i++) {
        int cnt = 32 / (i + 1);
        if (rem < cnt) break;
        rem -= cnt;
      }
      enc = (unsigned short)((i << 5) | rem);
    }
    cand[tid] = enc;
  }
  const int rloc = tid >> 4;
  const int l = tid & 15;
  const int row = blockIdx.x * 16 + rloc;   // 0..32767 = (b,h,t)
  const int b = row >> 14;
  const int h = (row >> 11) & 7;
  const int t = row & 2047;
  const int tt = t >> 1, p = t & 1;
  size_t rbase = (size_t)(b * 8 + h) * TSEQ;
  size_t base0 = ((rbase + tt) * 2 + p) * 32;
  size_t base1 = ((rbase + tt + 1024) * 2 + p) * 32;
  s0sh[rloc][l] = s1s[base0 + l];
  s0sh[rloc][l + 16] = s1s[base0 + l + 16];
  s1sh[rloc][l] = s1s[base1 + l];
  s1sh[rloc][l + 16] = s1s[base1 + l + 16];
  i0sh[rloc][l] = s1i[base0 + l];
  i0sh[rloc][l + 16] = s1i[base0 + l + 16];
  i1sh[rloc][l] = s1i[base1 + l];
  i1sh[rloc][l + 16] = s1i[base1 + l + 16];
  __syncthreads();
  u32 key[8];
#pragma unroll
  for (int s = 0; s < 8; s++) {
    int c = l + 16 * s;
    unsigned short e = cand[c];
    u32 kk = 0u;
    if (e != 0xFFFF) {
      float v = s0sh[rloc][e >> 5] + s1sh[rloc][e & 31];
      kk = (f2sort(v) & ~0xFFu) | (u32)s;
    }
    key[s] = kk;
  }
  const int wl = tid & 63;
  const int grp = wl & 48;
  float myw0 = 0.f, myw1 = 0.f;
  int myv0 = 0, myv1 = 0;
  for (int it = 0; it < 32; it++) {
    u32 lm = key[0];
#pragma unroll
    for (int s = 1; s < 8; s++) lm = key[s] > lm ? key[s] : lm;
    u32 gm = lm;
#pragma unroll
    for (int d = 1; d < 16; d <<= 1) {
      u32 o = (u32)__shfl_xor((int)gm, d);
      gm = o > gm ? o : gm;
    }
    u64 mask = __ballot(lm == gm);
    int owner = __ffsll((u64)((mask >> grp) & 0xFFFFull)) - 1;
    int swin = (int)(gm & 0xFFu);
    unsigned short e = cand[owner + 16 * swin];
    int wi = e >> 5, wj = e & 31;
    float score = sort2f(gm & ~0xFFu);
    int vidx = i0sh[rloc][wi] * 256 + i1sh[rloc][wj];
    bool isown = (l == owner);
#pragma unroll
    for (int s = 0; s < 8; s++)
      key[s] = (isown && s == swin) ? 0u : key[s];
    if (l == (it & 15)) {
      if (it < 16) { myw0 = score; myv0 = vidx; }
      else         { myw1 = score; myv1 = vidx; }
    }
  }
  // softmax over the 32 winners (descending -> max is winner 0 on lane grp)
  float m0 = __shfl(myw0, grp);
  float e0 = __expf(myw0 - m0);
  float e1 = __expf(myw1 - m0);
  float ssum = e0 + e1;
#pragma unroll
  for (int d = 1; d < 16; d <<= 1) ssum += __shfl_xor(ssum, d);
  float inv = 1.0f / ssum;
  float a0 = e0 * inv, a1 = e1 * inv;
  // gather + weighted sum: 128 floats/row, 8 per lane
  const float* vb = values + (((size_t)h) << 16) * 128 + l * 8;
  float4 acc0 = make_float4(0.f, 0.f, 0.f, 0.f);
  float4 acc1 = make_float4(0.f, 0.f, 0.f, 0.f);
#pragma unroll 8
  for (int k = 0; k < 32; k++) {
    int src = grp + (k & 15);
    int vi = __shfl((k < 16) ? myv0 : myv1, src);
    float wk = __shfl((k < 16) ? a0 : a1, src);
    const float* vp = vb + (size_t)vi * 128;
    float4 x0 = *(const float4*)(vp);
    float4 x1 = *(const float4*)(vp + 4);
    acc0.x += wk * x0.x; acc0.y += wk * x0.y;
    acc0.z += wk * x0.z; acc0.w += wk * x0.w;
    acc1.x += wk * x1.x; acc1.y += wk * x1.y;
    acc1.z += wk * x1.z; acc1.w += wk * x1.w;
  }
  float* op = headout + (size_t)(b * TSEQ + t) * 1024 + h * 128 + l * 8;
  *(float4*)(op) = acc0;
  *(float4*)(op + 4) = acc1;
}

// ---------------------------------------------------------------------------
extern "C" void kernel_launch(void* const* d_in, const int* in_sizes, int n_in,
                              void* d_out, int out_size, void* d_ws,
                              size_t ws_size, hipStream_t stream) {
  const float* x    = (const float*)d_in[0];   // (2,2048,1024)
  const float* Wq   = (const float*)d_in[1];   // (2048,1024)
  const float* keys = (const float*)d_in[2];   // (8,256,2,128)
  const float* vals = (const float*)d_in[3];   // (8,65536,128)
  const float* Wo   = (const float*)d_in[4];   // (1024,1024)
  const float* bo   = (const float*)d_in[5];   // (1024,)
  float* out = (float*)d_out;                  // (2,2048,1024) fp32
  char* ws = (char*)d_ws;
  float* Q    = (float*)(ws);                        // 32 MB: (4096,2048)
  float* Dbuf = (float*)(ws + (size_t)(32u << 20));  // 64 MB: (16,4096,256)
  float* s1s  = (float*)(ws + (size_t)(96u << 20));  // 8 MB
  int*   s1i  = (int*)(ws + (size_t)(104u << 20));   // 8 MB
  float* headout = (float*)(ws);                     // aliases Q (Q dead)

  // 1) Q = x @ Wq^T            (M=4096, N=2048, K=1024)
  gemm_nt<<<dim3(32, 64, 1), 256, 0, stream>>>(x, 1024, Wq, 1024, nullptr, Q,
                                               2048, 1024, 0);
  // 2) dots: 16 GEMMs          (M=4096, N=256, K=128) per (h,p)
  gemm_nt<<<dim3(4, 64, 16), 256, 0, stream>>>(Q, 2048, keys, 256, nullptr,
                                               Dbuf, 256, 128, 1);
  // 3) stage-1 top-32 of 256 per (hp,b,t)
  topk1<<<dim3(65536 / 16), 256, 0, stream>>>(Dbuf, s1s, s1i);
  // 4) stage-2 top-32 + softmax + value gather -> headout (4096,1024)
  topk2_gather<<<dim3(32768 / 16), 256, 0, stream>>>(s1s, s1i, vals, headout);
  // 5) out = headout @ Wo^T + bo
  gemm_nt<<<dim3(16, 64, 1), 256, 0, stream>>>(headout, 1024, Wo, 1024, bo,
                                               out, 1024, 1024, 0);
}

// Round 2
// 593.344 us; speedup vs baseline: 1.5618x; 1.5618x over previous
//
#include <hip/hip_runtime.h>

typedef unsigned int u32;
typedef unsigned long long u64;
typedef _Float16 f16;
typedef __attribute__((ext_vector_type(8))) _Float16 f16x8;
typedef __attribute__((ext_vector_type(4))) float f32x4;

#define TSEQ 2048
#define PAD 40  // LDS row stride in f16: 80 B -> b128 frag reads are <=2-way (free)

// monotone fp32 -> u32 map (order-preserving)
__device__ __forceinline__ u32 f2sort(float f) {
  u32 u = __float_as_uint(f);
  return u ^ ((u32)((int)u >> 31) | 0x80000000u);
}
__device__ __forceinline__ float sort2f(u32 u) {
  u ^= (u & 0x80000000u) ? 0x80000000u : 0xFFFFFFFFu;
  return __uint_as_float(u);
}

__device__ __forceinline__ f16x8 cvt8(float4 a, float4 b) {
  f16x8 r;
  r[0] = (f16)a.x; r[1] = (f16)a.y; r[2] = (f16)a.z; r[3] = (f16)a.w;
  r[4] = (f16)b.x; r[5] = (f16)b.y; r[6] = (f16)b.z; r[7] = (f16)b.w;
  return r;
}

// ---------------------------------------------------------------------------
// MFMA NT GEMM: C[m,n] = sum_k A[m,k]*B[n,k] (+bias[n]), fp32 in/out,
// f16 MFMA compute (16x16x32), fp32 accumulate. 128x128 tile, 256 thr,
// 4 waves each computing 64x64 via 4x4 MFMA fragments. BK=32.
// dots mode: blockIdx.z = h*2+p selects Q col slice / keys slice / D slab.
// ---------------------------------------------------------------------------
__global__ __launch_bounds__(256) void gemm_mfma_nt(
    const float* __restrict__ A, int lda,
    const float* __restrict__ B, int ldb,
    const float* __restrict__ bias,
    float* __restrict__ C, int ldc, int K, int dots) {
  if (dots) {
    int z = blockIdx.z;
    int h = z >> 1, p = z & 1;
    A += p * 1024 + h * 128;                 // Q column offset (lda=2048)
    B += (size_t)(h * 512 + p) * 128;        // keys[h,0,p,0], row stride 256
    C += (size_t)z * 4096 * 256;             // D slab per (h,p)
  }
  __shared__ f16 As[128 * PAD];
  __shared__ f16 Bs[128 * PAD];
  const int tid = threadIdx.x;
  const int m0 = blockIdx.y << 7, n0 = blockIdx.x << 7;
  // staging: thread t loads 16 contiguous fp32 of row (t>>1), k-half (t&1)
  const int srow = tid >> 1;
  const int sk = (tid & 1) << 4;
  const float* Ap = A + (size_t)(m0 + srow) * lda + sk;
  const float* Bp = B + (size_t)(n0 + srow) * ldb + sk;
  const int lane = tid & 63;
  const int wave = tid >> 6;
  const int wm = (wave >> 1) << 6;           // wave 64x64 block in tile
  const int wn = (wave & 1) << 6;
  const int fm = lane & 15;                  // fragment row/col
  const int fk = (lane >> 4) << 3;           // fragment k base (quad*8)
  f32x4 acc[4][4] = {};
  for (int k0 = 0; k0 < K; k0 += 32) {
    float4 av0 = *(const float4*)(Ap + k0);
    float4 av1 = *(const float4*)(Ap + k0 + 4);
    float4 av2 = *(const float4*)(Ap + k0 + 8);
    float4 av3 = *(const float4*)(Ap + k0 + 12);
    float4 bv0 = *(const float4*)(Bp + k0);
    float4 bv1 = *(const float4*)(Bp + k0 + 4);
    float4 bv2 = *(const float4*)(Bp + k0 + 8);
    float4 bv3 = *(const float4*)(Bp + k0 + 12);
    __syncthreads();                         // prev tile fully consumed
    *(f16x8*)&As[srow * PAD + sk] = cvt8(av0, av1);
    *(f16x8*)&As[srow * PAD + sk + 8] = cvt8(av2, av3);
    *(f16x8*)&Bs[srow * PAD + sk] = cvt8(bv0, bv1);
    *(f16x8*)&Bs[srow * PAD + sk + 8] = cvt8(bv2, bv3);
    __syncthreads();
    f16x8 af[4], bf[4];
#pragma unroll
    for (int mi = 0; mi < 4; mi++)
      af[mi] = *(const f16x8*)&As[(wm + mi * 16 + fm) * PAD + fk];
#pragma unroll
    for (int nj = 0; nj < 4; nj++)
      bf[nj] = *(const f16x8*)&Bs[(wn + nj * 16 + fm) * PAD + fk];
#pragma unroll
    for (int mi = 0; mi < 4; mi++)
#pragma unroll
      for (int nj = 0; nj < 4; nj++)
        acc[mi][nj] = __builtin_amdgcn_mfma_f32_16x16x32_f16(
            af[mi], bf[nj], acc[mi][nj], 0, 0, 0);
  }
  float bb[4];
#pragma unroll
  for (int nj = 0; nj < 4; nj++)
    bb[nj] = bias ? bias[n0 + wn + nj * 16 + fm] : 0.f;
#pragma unroll
  for (int mi = 0; mi < 4; mi++) {
#pragma unroll
    for (int r = 0; r < 4; r++) {
      int row = m0 + wm + mi * 16 + ((lane >> 4) << 2) + r;
      float* cp = C + (size_t)row * ldc + n0 + wn + fm;
#pragma unroll
      for (int nj = 0; nj < 4; nj++) cp[nj * 16] = acc[mi][nj][r] + bb[nj];
    }
  }
}

// ---------------------------------------------------------------------------
// Stage-1 top-32 of 256 per row. 16 lanes/row, 4 rows/wave, 16 rows/block.
// ---------------------------------------------------------------------------
__global__ __launch_bounds__(256) void topk1(
    const float* __restrict__ D, float* __restrict__ s1score,
    int* __restrict__ s1idx) {
  const int tid = threadIdx.x;
  const int rloc = tid >> 4;
  const int l = tid & 15;
  const int wid = blockIdx.x * 16 + rloc;   // 0..65535 = (hp, b, t)
  const float* row = D + (size_t)wid * 256;
  u32 key[16];
#pragma unroll
  for (int s = 0; s < 16; s++) {
    float v = row[l + 16 * s];
    key[s] = (f2sort(v) & ~0xFFu) | (u32)s;
  }
  const int wl = tid & 63;
  const int grp = wl & 48;                  // group base lane in wave
  float myw0 = 0.f, myw1 = 0.f;
  int myi0 = 0, myi1 = 0;
  for (int it = 0; it < 32; it++) {
    u32 lm = key[0];
#pragma unroll
    for (int s = 1; s < 16; s++) lm = key[s] > lm ? key[s] : lm;
    u32 gm = lm;
#pragma unroll
    for (int d = 1; d < 16; d <<= 1) {
      u32 o = (u32)__shfl_xor((int)gm, d);
      gm = o > gm ? o : gm;
    }
    u64 mask = __ballot(lm == gm);
    int owner = __ffsll((u64)((mask >> grp) & 0xFFFFull)) - 1;  // lane in grp
    int swin = (int)(gm & 0xFFu);
    int idx = swin * 16 + owner;            // element index n
    float score = sort2f(gm & ~0xFFu);
    bool isown = (l == owner);
#pragma unroll
    for (int s = 0; s < 16; s++)
      key[s] = (isown && s == swin) ? 0u : key[s];
    if (l == (it & 15)) {
      if (it < 16) { myw0 = score; myi0 = idx; }
      else         { myw1 = score; myi1 = idx; }
    }
  }
  // wid = hp*4096 + b*2048 + t  ->  output row ((b*8+h)*2048+t)*2+p
  int hp = wid >> 12, r = wid & 4095;
  int h = hp >> 1, p = hp & 1;
  int b = r >> 11, t = r & 2047;
  size_t orow = ((((size_t)(b * 8 + h)) * TSEQ + t) * 2 + p) * 32;
  s1score[orow + l] = myw0;
  s1score[orow + l + 16] = myw1;
  s1idx[orow + l] = myi0;
  s1idx[orow + l + 16] = myi1;
}

// ---------------------------------------------------------------------------
// Stage-2: combine halves, top-32 of 32x32 sum grid (dominance frontier:
// (i+1)(j+1)<=32 -> 119 candidates), softmax, gather values, weighted sum.
// ---------------------------------------------------------------------------
__global__ __launch_bounds__(256) void topk2_gather(
    const float* __restrict__ s1s, const int* __restrict__ s1i,
    const float* __restrict__ values, float* __restrict__ headout) {
  __shared__ unsigned short cand[128];      // (i<<5)|j, 0xFFFF = pad
  __shared__ float s0sh[16][32];
  __shared__ float s1sh[16][32];
  __shared__ int i0sh[16][32];
  __shared__ int i1sh[16][32];
  const int tid = threadIdx.x;
  if (tid < 128) {
    int c = tid;
    unsigned short enc = 0xFFFF;
    if (c < 119) {
      int rem = c, i = 0;
      for (i = 0; i < 32; i++) {
        int cnt = 32 / (i + 1);
        if (rem < cnt) break;
        rem -= cnt;
      }
      enc = (unsigned short)((i << 5) | rem);
    }
    cand[tid] = enc;
  }
  const int rloc = tid >> 4;
  const int l = tid & 15;
  const int row = blockIdx.x * 16 + rloc;   // 0..32767 = (b,h,t)
  const int b = row >> 14;
  const int h = (row >> 11) & 7;
  const int t = row & 2047;
  const int tt = t >> 1, p = t & 1;
  size_t rbase = (size_t)(b * 8 + h) * TSEQ;
  size_t base0 = ((rbase + tt) * 2 + p) * 32;
  size_t base1 = ((rbase + tt + 1024) * 2 + p) * 32;
  s0sh[rloc][l] = s1s[base0 + l];
  s0sh[rloc][l + 16] = s1s[base0 + l + 16];
  s1sh[rloc][l] = s1s[base1 + l];
  s1sh[rloc][l + 16] = s1s[base1 + l + 16];
  i0sh[rloc][l] = s1i[base0 + l];
  i0sh[rloc][l + 16] = s1i[base0 + l + 16];
  i1sh[rloc][l] = s1i[base1 + l];
  i1sh[rloc][l + 16] = s1i[base1 + l + 16];
  __syncthreads();
  u32 key[8];
#pragma unroll
  for (int s = 0; s < 8; s++) {
    int c = l + 16 * s;
    unsigned short e = cand[c];
    u32 kk = 0u;
    if (e != 0xFFFF) {
      float v = s0sh[rloc][e >> 5] + s1sh[rloc][e & 31];
      kk = (f2sort(v) & ~0xFFu) | (u32)s;
    }
    key[s] = kk;
  }
  const int wl = tid & 63;
  const int grp = wl & 48;
  float myw0 = 0.f, myw1 = 0.f;
  int myv0 = 0, myv1 = 0;
  for (int it = 0; it < 32; it++) {
    u32 lm = key[0];
#pragma unroll
    for (int s = 1; s < 8; s++) lm = key[s] > lm ? key[s] : lm;
    u32 gm = lm;
#pragma unroll
    for (int d = 1; d < 16; d <<= 1) {
      u32 o = (u32)__shfl_xor((int)gm, d);
      gm = o > gm ? o : gm;
    }
    u64 mask = __ballot(lm == gm);
    int owner = __ffsll((u64)((mask >> grp) & 0xFFFFull)) - 1;
    int swin = (int)(gm & 0xFFu);
    unsigned short e = cand[owner + 16 * swin];
    int wi = e >> 5, wj = e & 31;
    float score = sort2f(gm & ~0xFFu);
    int vidx = i0sh[rloc][wi] * 256 + i1sh[rloc][wj];
    bool isown = (l == owner);
#pragma unroll
    for (int s = 0; s < 8; s++)
      key[s] = (isown && s == swin) ? 0u : key[s];
    if (l == (it & 15)) {
      if (it < 16) { myw0 = score; myv0 = vidx; }
      else         { myw1 = score; myv1 = vidx; }
    }
  }
  // softmax over the 32 winners (descending -> max is winner 0 on lane grp)
  float m0 = __shfl(myw0, grp);
  float e0 = __expf(myw0 - m0);
  float e1 = __expf(myw1 - m0);
  float ssum = e0 + e1;
#pragma unroll
  for (int d = 1; d < 16; d <<= 1) ssum += __shfl_xor(ssum, d);
  float inv = 1.0f / ssum;
  float a0 = e0 * inv, a1 = e1 * inv;
  // gather + weighted sum: 128 floats/row, 8 per lane
  const float* vb = values + (((size_t)h) << 16) * 128 + l * 8;
  float4 acc0 = make_float4(0.f, 0.f, 0.f, 0.f);
  float4 acc1 = make_float4(0.f, 0.f, 0.f, 0.f);
#pragma unroll 8
  for (int k = 0; k < 32; k++) {
    int src = grp + (k & 15);
    int vi = __shfl((k < 16) ? myv0 : myv1, src);
    float wk = __shfl((k < 16) ? a0 : a1, src);
    const float* vp = vb + (size_t)vi * 128;
    float4 x0 = *(const float4*)(vp);
    float4 x1 = *(const float4*)(vp + 4);
    acc0.x += wk * x0.x; acc0.y += wk * x0.y;
    acc0.z += wk * x0.z; acc0.w += wk * x0.w;
    acc1.x += wk * x1.x; acc1.y += wk * x1.y;
    acc1.z += wk * x1.z; acc1.w += wk * x1.w;
  }
  float* op = headout + (size_t)(b * TSEQ + t) * 1024 + h * 128 + l * 8;
  *(float4*)(op) = acc0;
  *(float4*)(op + 4) = acc1;
}

// ---------------------------------------------------------------------------
extern "C" void kernel_launch(void* const* d_in, const int* in_sizes, int n_in,
                              void* d_out, int out_size, void* d_ws,
                              size_t ws_size, hipStream_t stream) {
  const float* x    = (const float*)d_in[0];   // (2,2048,1024)
  const float* Wq   = (const float*)d_in[1];   // (2048,1024)
  const float* keys = (const float*)d_in[2];   // (8,256,2,128)
  const float* vals = (const float*)d_in[3];   // (8,65536,128)
  const float* Wo   = (const float*)d_in[4];   // (1024,1024)
  const float* bo   = (const float*)d_in[5];   // (1024,)
  float* out = (float*)d_out;                  // (2,2048,1024) fp32
  char* ws = (char*)d_ws;
  float* Q    = (float*)(ws);                        // 32 MB: (4096,2048)
  float* Dbuf = (float*)(ws + (size_t)(32u << 20));  // 64 MB: (16,4096,256)
  float* s1s  = (float*)(ws + (size_t)(96u << 20));  // 8 MB
  int*   s1i  = (int*)(ws + (size_t)(104u << 20));   // 8 MB
  float* headout = (float*)(ws);                     // aliases Q (Q dead)

  // 1) Q = x @ Wq^T            (M=4096, N=2048, K=1024)
  gemm_mfma_nt<<<dim3(16, 32, 1), 256, 0, stream>>>(x, 1024, Wq, 1024, nullptr,
                                                    Q, 2048, 1024, 0);
  // 2) dots: 16 GEMMs          (M=4096, N=256, K=128) per (h,p)
  gemm_mfma_nt<<<dim3(2, 32, 16), 256, 0, stream>>>(Q, 2048, keys, 256,
                                                    nullptr, Dbuf, 256, 128, 1);
  // 3) stage-1 top-32 of 256 per (hp,b,t)
  topk1<<<dim3(65536 / 16), 256, 0, stream>>>(Dbuf, s1s, s1i);
  // 4) stage-2 top-32 + softmax + value gather -> headout (4096,1024)
  topk2_gather<<<dim3(32768 / 16), 256, 0, stream>>>(s1s, s1i, vals, headout);
  // 5) out = headout @ Wo^T + bo
  gemm_mfma_nt<<<dim3(8, 32, 1), 256, 0, stream>>>(headout, 1024, Wo, 1024, bo,
                                                   out, 1024, 1024, 0);
}

// Round 3
// 570.325 us; speedup vs baseline: 1.6248x; 1.0404x over previous
//
#include <hip/hip_runtime.h>

typedef unsigned int u32;
typedef unsigned long long u64;
typedef _Float16 f16;
typedef __attribute__((ext_vector_type(4))) _Float16 f16x4;
typedef __attribute__((ext_vector_type(8))) _Float16 f16x8;
typedef __attribute__((ext_vector_type(4))) float f32x4;
typedef const __attribute__((address_space(1))) void* gp_t;
typedef __attribute__((address_space(3))) void* lp_t;

#define TSEQ 2048

// monotone fp32 -> u32 map (order-preserving)
__device__ __forceinline__ u32 f2sort(float f) {
  u32 u = __float_as_uint(f);
  return u ^ ((u32)((int)u >> 31) | 0x80000000u);
}
__device__ __forceinline__ float sort2f(u32 u) {
  u ^= (u & 0x80000000u) ? 0x80000000u : 0xFFFFFFFFu;
  return __uint_as_float(u);
}

__device__ __forceinline__ void glds16(const f16* g, f16* l) {
  // async global->LDS, 16B per lane; LDS dest = wave-uniform base + lane*16
  __builtin_amdgcn_global_load_lds((gp_t)g, (lp_t)l, 16, 0, 0);
}

// ---------------------------------------------------------------------------
// fp32 -> f16 converter for x (1048576 f4), Wq (524288), Wo (262144),
// keys (131072). One float4 per thread; grid = 7680 blocks exactly.
// ---------------------------------------------------------------------------
__global__ __launch_bounds__(256) void cvt_all(
    const float* __restrict__ x, const float* __restrict__ wq,
    const float* __restrict__ wo, const float* __restrict__ ky,
    f16* __restrict__ xd, f16* __restrict__ wqd, f16* __restrict__ wod,
    f16* __restrict__ kyd) {
  int g = blockIdx.x * 256 + threadIdx.x;
  const float* s;
  f16* d;
  int off;
  if (g < 1048576)      { s = x;  d = xd;  off = g; }
  else if (g < 1572864) { s = wq; d = wqd; off = g - 1048576; }
  else if (g < 1835008) { s = wo; d = wod; off = g - 1572864; }
  else                  { s = ky; d = kyd; off = g - 1835008; }
  float4 v = ((const float4*)s)[off];
  f16x4 o;
  o[0] = (f16)v.x; o[1] = (f16)v.y; o[2] = (f16)v.z; o[3] = (f16)v.w;
  ((f16x4*)d)[off] = o;
}

// ---------------------------------------------------------------------------
// m97-style f16 NT GEMM: C[m,n] = sum_k A[m,k]*B[n,k] (+bias), A/B f16,
// C fp32 or f16. 128x128 tile, BK=32, global_load_lds width=16,
// 4 waves x (64x64 via 4x4 16x16x32 MFMA).
// ---------------------------------------------------------------------------
__global__ __launch_bounds__(256) void gemm_f16(
    const f16* __restrict__ A, int lda, const f16* __restrict__ B, int ldb,
    const float* __restrict__ bias, void* __restrict__ Cv, int ldc, int K,
    int c_f16) {
  __shared__ f16 As[128 * 32];
  __shared__ f16 Bs[128 * 32];
  const int tid = threadIdx.x;
  const int lane = tid & 63, wave = tid >> 6;
  const int m0 = blockIdx.y << 7, n0 = blockIdx.x << 7;
  // staging: chunk = (wave*2+c)*64 + lane; row = chunk>>2, sub = chunk&3
  const int c0 = wave * 128 + lane, c1 = c0 + 64;
  const int r0 = c0 >> 2, s0 = c0 & 3;
  const int r1 = c1 >> 2, s1 = c1 & 3;
  const f16* Ab = A + (size_t)m0 * lda;
  const f16* Bb = B + (size_t)n0 * ldb;
  const int fm = lane & 15, fq = lane >> 4, fk = fq << 3;
  const int wm = (wave >> 1) << 6, wn = (wave & 1) << 6;
  f32x4 acc[4][4] = {};
  for (int k0 = 0; k0 < K; k0 += 32) {
    __syncthreads();  // prev tile fully consumed
    glds16(Ab + (size_t)r0 * lda + k0 + s0 * 8, As + (size_t)c0 * 8 - lane * 8);
    glds16(Ab + (size_t)r1 * lda + k0 + s1 * 8, As + (size_t)c1 * 8 - lane * 8);
    glds16(Bb + (size_t)r0 * ldb + k0 + s0 * 8, Bs + (size_t)c0 * 8 - lane * 8);
    glds16(Bb + (size_t)r1 * ldb + k0 + s1 * 8, Bs + (size_t)c1 * 8 - lane * 8);
    __syncthreads();  // barrier drains vmcnt -> LDS visible
    f16x8 af[4], bf[4];
#pragma unroll
    for (int mi = 0; mi < 4; mi++)
      af[mi] = *(const f16x8*)&As[(wm + mi * 16 + fm) * 32 + fk];
#pragma unroll
    for (int nj = 0; nj < 4; nj++)
      bf[nj] = *(const f16x8*)&Bs[(wn + nj * 16 + fm) * 32 + fk];
#pragma unroll
    for (int mi = 0; mi < 4; mi++)
#pragma unroll
      for (int nj = 0; nj < 4; nj++)
        acc[mi][nj] = __builtin_amdgcn_mfma_f32_16x16x32_f16(
            af[mi], bf[nj], acc[mi][nj], 0, 0, 0);
  }
  if (c_f16) {
    f16* C = (f16*)Cv;
#pragma unroll
    for (int mi = 0; mi < 4; mi++)
#pragma unroll
      for (int r = 0; r < 4; r++) {
        int row = m0 + wm + mi * 16 + fq * 4 + r;
        f16* cp = C + (size_t)row * ldc + n0 + wn + fm;
#pragma unroll
        for (int nj = 0; nj < 4; nj++) cp[nj * 16] = (f16)acc[mi][nj][r];
      }
  } else {
    float* C = (float*)Cv;
    float bb[4];
#pragma unroll
    for (int nj = 0; nj < 4; nj++)
      bb[nj] = bias ? bias[n0 + wn + nj * 16 + fm] : 0.f;
#pragma unroll
    for (int mi = 0; mi < 4; mi++)
#pragma unroll
      for (int r = 0; r < 4; r++) {
        int row = m0 + wm + mi * 16 + fq * 4 + r;
        float* cp = C + (size_t)row * ldc + n0 + wn + fm;
#pragma unroll
        for (int nj = 0; nj < 4; nj++) cp[nj * 16] = acc[mi][nj][r] + bb[nj];
      }
  }
}

// ---------------------------------------------------------------------------
// Fused dots + stage-1 top-32. Block = 64 rows x 256 cols, K=128.
// Wave computes 16 rows x 256 cols (16 MFMA frags); score row (256 values)
// lives as 16 lanes x 16 regs within one quad -> in-register top-k.
// Output sorted descending (required by stage 2).
// ---------------------------------------------------------------------------
__global__ __launch_bounds__(256) void dots_topk1(
    const f16* __restrict__ Q,      // (4096, 2048)
    const f16* __restrict__ keysf,  // (8,256,2,128)
    float* __restrict__ s1s, int* __restrict__ s1i) {
  __shared__ f16 As[64 * 32];
  __shared__ f16 Bs[256 * 32];
  const int tid = threadIdx.x;
  const int lane = tid & 63, wave = tid >> 6;
  const int z = blockIdx.y;  // h*2+p
  const int h = z >> 1, p = z & 1;
  const int m0 = blockIdx.x << 6;
  const f16* Aq = Q + (size_t)m0 * 2048 + p * 1024 + h * 128;
  const f16* Bk = keysf + ((size_t)h * 512 + p) * 128;  // row stride 256 f16
  const int cA = wave * 64 + lane;
  const int rA = cA >> 2, sA = cA & 3;
  const int fm = lane & 15, fq = lane >> 4, fk = fq << 3;
  f32x4 acc[16] = {};
  for (int k0 = 0; k0 < 128; k0 += 32) {
    __syncthreads();
    glds16(Aq + (size_t)rA * 2048 + k0 + sA * 8, As + (size_t)cA * 8 - lane * 8);
#pragma unroll
    for (int c = 0; c < 4; c++) {
      int cB = (wave * 4 + c) * 64 + lane;
      int rB = cB >> 2, sB = cB & 3;
      glds16(Bk + (size_t)rB * 256 + k0 + sB * 8,
             Bs + (size_t)cB * 8 - lane * 8);
    }
    __syncthreads();
    f16x8 af = *(const f16x8*)&As[(wave * 16 + fm) * 32 + fk];
#pragma unroll
    for (int j = 0; j < 16; j++) {
      f16x8 bf = *(const f16x8*)&Bs[(j * 16 + fm) * 32 + fk];
      acc[j] = __builtin_amdgcn_mfma_f32_16x16x32_f16(af, bf, acc[j], 0, 0, 0);
    }
  }
  // top-32 per row; quad fq handles rows m0 + wave*16 + fq*4 + r
  const int grp = lane & 48;
  for (int r = 0; r < 4; r++) {
    u32 key[16];
#pragma unroll
    for (int j = 0; j < 16; j++)
      key[j] = (f2sort(acc[j][r]) & ~0xFFu) | (u32)j;
    float myw0 = 0.f, myw1 = 0.f;
    int myi0 = 0, myi1 = 0;
    for (int it = 0; it < 32; it++) {
      u32 lm = key[0];
#pragma unroll
      for (int j = 1; j < 16; j++) lm = key[j] > lm ? key[j] : lm;
      u32 gm = lm;
#pragma unroll
      for (int d = 1; d < 16; d <<= 1) {
        u32 o = (u32)__shfl_xor((int)gm, d);
        gm = o > gm ? o : gm;
      }
      u64 mask = __ballot(lm == gm);
      int owner = __ffsll((u64)((mask >> grp) & 0xFFFFull)) - 1;
      int swin = (int)(gm & 0xFFu);
      int idx = swin * 16 + owner;
      float score = sort2f(gm & ~0xFFu);
      bool isown = (fm == owner);
#pragma unroll
      for (int j = 0; j < 16; j++)
        key[j] = (isown && j == swin) ? 0u : key[j];
      if (fm == (it & 15)) {
        if (it < 16) { myw0 = score; myi0 = idx; }
        else         { myw1 = score; myi1 = idx; }
      }
    }
    int m = m0 + wave * 16 + (fq << 2) + r;
    int b = m >> 11, t = m & 2047;
    size_t orow = ((((size_t)(b * 8 + h)) * TSEQ + t) * 2 + p) * 32;
    s1s[orow + fm] = myw0;
    s1s[orow + fm + 16] = myw1;
    s1i[orow + fm] = myi0;
    s1i[orow + fm + 16] = myi1;
  }
}

// ---------------------------------------------------------------------------
// Stage-2: combine halves, top-32 of 32x32 sum grid (dominance frontier:
// (i+1)(j+1)<=32 -> 119 candidates), softmax, gather values, weighted sum.
// Output headout as f16.
// ---------------------------------------------------------------------------
__global__ __launch_bounds__(256) void topk2_gather(
    const float* __restrict__ s1s, const int* __restrict__ s1i,
    const float* __restrict__ values, f16* __restrict__ headout) {
  __shared__ unsigned short cand[128];  // (i<<5)|j, 0xFFFF = pad
  __shared__ float s0sh[16][32];
  __shared__ float s1sh[16][32];
  __shared__ int i0sh[16][32];
  __shared__ int i1sh[16][32];
  const int tid = threadIdx.x;
  if (tid < 128) {
    int c = tid;
    unsigned short enc = 0xFFFF;
    if (c < 119) {
      int rem = c, i = 0;
      for (i = 0; i < 32; i++) {
        int cnt = 32 / (i + 1);
        if (rem < cnt) break;
        rem -= cnt;
      }
      enc = (unsigned short)((i << 5) | rem);
    }
    cand[tid] = enc;
  }
  const int rloc = tid >> 4;
  const int l = tid & 15;
  const int row = blockIdx.x * 16 + rloc;  // (b,h,t)
  const int b = row >> 14;
  const int h = (row >> 11) & 7;
  const int t = row & 2047;
  const int tt = t >> 1, p = t & 1;
  size_t rbase = (size_t)(b * 8 + h) * TSEQ;
  size_t base0 = ((rbase + tt) * 2 + p) * 32;
  size_t base1 = ((rbase + tt + 1024) * 2 + p) * 32;
  s0sh[rloc][l] = s1s[base0 + l];
  s0sh[rloc][l + 16] = s1s[base0 + l + 16];
  s1sh[rloc][l] = s1s[base1 + l];
  s1sh[rloc][l + 16] = s1s[base1 + l + 16];
  i0sh[rloc][l] = s1i[base0 + l];
  i0sh[rloc][l + 16] = s1i[base0 + l + 16];
  i1sh[rloc][l] = s1i[base1 + l];
  i1sh[rloc][l + 16] = s1i[base1 + l + 16];
  __syncthreads();
  u32 key[8];
#pragma unroll
  for (int s = 0; s < 8; s++) {
    int c = l + 16 * s;
    unsigned short e = cand[c];
    u32 kk = 0u;
    if (e != 0xFFFF) {
      float v = s0sh[rloc][e >> 5] + s1sh[rloc][e & 31];
      kk = (f2sort(v) & ~0xFFu) | (u32)s;
    }
    key[s] = kk;
  }
  const int grp = tid & 48;
  float myw0 = 0.f, myw1 = 0.f;
  int myv0 = 0, myv1 = 0;
  for (int it = 0; it < 32; it++) {
    u32 lm = key[0];
#pragma unroll
    for (int s = 1; s < 8; s++) lm = key[s] > lm ? key[s] : lm;
    u32 gm = lm;
#pragma unroll
    for (int d = 1; d < 16; d <<= 1) {
      u32 o = (u32)__shfl_xor((int)gm, d);
      gm = o > gm ? o : gm;
    }
    u64 mask = __ballot(lm == gm);
    int owner = __ffsll((u64)((mask >> grp) & 0xFFFFull)) - 1;
    int swin = (int)(gm & 0xFFu);
    unsigned short e = cand[owner + 16 * swin];
    int wi = e >> 5, wj = e & 31;
    float score = sort2f(gm & ~0xFFu);
    int vidx = i0sh[rloc][wi] * 256 + i1sh[rloc][wj];
    bool isown = (l == owner);
#pragma unroll
    for (int s = 0; s < 8; s++)
      key[s] = (isown && s == swin) ? 0u : key[s];
    if (l == (it & 15)) {
      if (it < 16) { myw0 = score; myv0 = vidx; }
      else         { myw1 = score; myv1 = vidx; }
    }
  }
  float m0 = __shfl(myw0, grp);
  float e0 = __expf(myw0 - m0);
  float e1 = __expf(myw1 - m0);
  float ssum = e0 + e1;
#pragma unroll
  for (int d = 1; d < 16; d <<= 1) ssum += __shfl_xor(ssum, d);
  float inv = 1.0f / ssum;
  float a0 = e0 * inv, a1 = e1 * inv;
  const float* vb = values + (((size_t)h) << 16) * 128 + l * 8;
  float4 acc0 = make_float4(0.f, 0.f, 0.f, 0.f);
  float4 acc1 = make_float4(0.f, 0.f, 0.f, 0.f);
#pragma unroll 8
  for (int k = 0; k < 32; k++) {
    int src = grp + (k & 15);
    int vi = __shfl((k < 16) ? myv0 : myv1, src);
    float wk = __shfl((k < 16) ? a0 : a1, src);
    const float* vp = vb + (size_t)vi * 128;
    float4 x0 = *(const float4*)(vp);
    float4 x1 = *(const float4*)(vp + 4);
    acc0.x += wk * x0.x; acc0.y += wk * x0.y;
    acc0.z += wk * x0.z; acc0.w += wk * x0.w;
    acc1.x += wk * x1.x; acc1.y += wk * x1.y;
    acc1.z += wk * x1.z; acc1.w += wk * x1.w;
  }
  f16x8 o;
  o[0] = (f16)acc0.x; o[1] = (f16)acc0.y; o[2] = (f16)acc0.z; o[3] = (f16)acc0.w;
  o[4] = (f16)acc1.x; o[5] = (f16)acc1.y; o[6] = (f16)acc1.z; o[7] = (f16)acc1.w;
  f16* op = headout + (size_t)(b * TSEQ + t) * 1024 + h * 128 + l * 8;
  *(f16x8*)op = o;
}

// ---------------------------------------------------------------------------
extern "C" void kernel_launch(void* const* d_in, const int* in_sizes, int n_in,
                              void* d_out, int out_size, void* d_ws,
                              size_t ws_size, hipStream_t stream) {
  const float* x    = (const float*)d_in[0];  // (2,2048,1024)
  const float* Wq   = (const float*)d_in[1];  // (2048,1024)
  const float* keys = (const float*)d_in[2];  // (8,256,2,128)
  const float* vals = (const float*)d_in[3];  // (8,65536,128)
  const float* Wo   = (const float*)d_in[4];  // (1024,1024)
  const float* bo   = (const float*)d_in[5];  // (1024,)
  float* out = (float*)d_out;                 // (2,2048,1024) fp32
  char* ws = (char*)d_ws;
  f16*   xf  = (f16*)(ws);                         // 8 MB
  f16*   wqf = (f16*)(ws + (size_t)(8u << 20));    // 4 MB
  f16*   wof = (f16*)(ws + (size_t)(12u << 20));   // 2 MB
  f16*   kyf = (f16*)(ws + (size_t)(14u << 20));   // 1 MB
  f16*   Qf  = (f16*)(ws + (size_t)(16u << 20));   // 16 MB (4096x2048)
  float* s1s = (float*)(ws + (size_t)(32u << 20)); // 8 MB
  int*   s1i = (int*)(ws + (size_t)(40u << 20));   // 8 MB
  f16*   hof = (f16*)(ws + (size_t)(48u << 20));   // 8 MB (4096x1024)

  // 0) fp32 -> f16 for x, Wq, Wo, keys
  cvt_all<<<dim3(7680), 256, 0, stream>>>(x, Wq, Wo, keys, xf, wqf, wof, kyf);
  // 1) Q = x @ Wq^T  (M=4096,N=2048,K=1024), f16 out
  gemm_f16<<<dim3(16, 32), 256, 0, stream>>>(xf, 1024, wqf, 1024, nullptr, Qf,
                                             2048, 1024, 1);
  // 2) dots + stage-1 top-32 fused (per (h,p): M=4096,N=256,K=128)
  dots_topk1<<<dim3(64, 16), 256, 0, stream>>>(Qf, kyf, s1s, s1i);
  // 3) stage-2 top-32 + softmax + gather -> headout f16
  topk2_gather<<<dim3(32768 / 16), 256, 0, stream>>>(s1s, s1i, vals, hof);
  // 4) out = headout @ Wo^T + bo  (M=4096,N=1024,K=1024), fp32 out
  gemm_f16<<<dim3(8, 32), 256, 0, stream>>>(hof, 1024, wof, 1024, bo, out,
                                            1024, 1024, 0);
}

// Round 4
// 566.700 us; speedup vs baseline: 1.6352x; 1.0064x over previous
//
#include <hip/hip_runtime.h>

typedef unsigned int u32;
typedef unsigned long long u64;
typedef _Float16 f16;
typedef __attribute__((ext_vector_type(4))) _Float16 f16x4;
typedef __attribute__((ext_vector_type(8))) _Float16 f16x8;
typedef __attribute__((ext_vector_type(4))) float f32x4;
typedef const __attribute__((address_space(1))) void* gp_t;
typedef __attribute__((address_space(3))) void* lp_t;

#define TSEQ 2048

// monotone fp32 -> u32 map (order-preserving)
__device__ __forceinline__ u32 f2sort(float f) {
  u32 u = __float_as_uint(f);
  return u ^ ((u32)((int)u >> 31) | 0x80000000u);
}
__device__ __forceinline__ float sort2f(u32 u) {
  u ^= (u & 0x80000000u) ? 0x80000000u : 0xFFFFFFFFu;
  return __uint_as_float(u);
}

__device__ __forceinline__ void glds16(const f16* g, f16* l) {
  __builtin_amdgcn_global_load_lds((gp_t)g, (lp_t)l, 16, 0, 0);
}

// max across each 16-lane DPP row, result broadcast to all 16 lanes.
// 4x (dpp row_shr + v_max_u32) leaves lane15 with the row max; one
// ds_swizzle (addr = (lane&0x10)|0xF) broadcasts it.
__device__ __forceinline__ u32 dppmax16(u32 v) {
  u32 t;
  t = (u32)__builtin_amdgcn_update_dpp(0, (int)v, 0x111, 0xF, 0xF, true);
  v = v > t ? v : t;
  t = (u32)__builtin_amdgcn_update_dpp(0, (int)v, 0x112, 0xF, 0xF, true);
  v = v > t ? v : t;
  t = (u32)__builtin_amdgcn_update_dpp(0, (int)v, 0x114, 0xF, 0xF, true);
  v = v > t ? v : t;
  t = (u32)__builtin_amdgcn_update_dpp(0, (int)v, 0x118, 0xF, 0xF, true);
  v = v > t ? v : t;
  return (u32)__builtin_amdgcn_ds_swizzle((int)v, 0x1F0);
}
// sum across each 16-lane row, broadcast to all 16 lanes (0-fill = +0.0)
__device__ __forceinline__ float dppsum16(float v) {
  float t;
  t = __int_as_float(
      __builtin_amdgcn_update_dpp(0, __float_as_int(v), 0x111, 0xF, 0xF, true));
  v += t;
  t = __int_as_float(
      __builtin_amdgcn_update_dpp(0, __float_as_int(v), 0x112, 0xF, 0xF, true));
  v += t;
  t = __int_as_float(
      __builtin_amdgcn_update_dpp(0, __float_as_int(v), 0x114, 0xF, 0xF, true));
  v += t;
  t = __int_as_float(
      __builtin_amdgcn_update_dpp(0, __float_as_int(v), 0x118, 0xF, 0xF, true));
  v += t;
  return __int_as_float(__builtin_amdgcn_ds_swizzle(__float_as_int(v), 0x1F0));
}

// ---------------------------------------------------------------------------
// fp32 -> f16: x (1048576 f4), Wq (524288), Wo (262144), keys (131072),
// values (16777216). grid = 73216 blocks exactly.
// ---------------------------------------------------------------------------
__global__ __launch_bounds__(256) void cvt_all(
    const float* __restrict__ x, const float* __restrict__ wq,
    const float* __restrict__ wo, const float* __restrict__ ky,
    const float* __restrict__ vl, f16* __restrict__ xd, f16* __restrict__ wqd,
    f16* __restrict__ wod, f16* __restrict__ kyd, f16* __restrict__ vld) {
  int g = blockIdx.x * 256 + threadIdx.x;
  const float* s;
  f16* d;
  int off;
  if (g >= 1966080)     { s = vl; d = vld; off = g - 1966080; }
  else if (g < 1048576) { s = x;  d = xd;  off = g; }
  else if (g < 1572864) { s = wq; d = wqd; off = g - 1048576; }
  else if (g < 1835008) { s = wo; d = wod; off = g - 1572864; }
  else                  { s = ky; d = kyd; off = g - 1835008; }
  float4 v = ((const float4*)s)[off];
  f16x4 o;
  o[0] = (f16)v.x; o[1] = (f16)v.y; o[2] = (f16)v.z; o[3] = (f16)v.w;
  ((f16x4*)d)[off] = o;
}

// ---------------------------------------------------------------------------
// m97-style f16 NT GEMM: C[m,n] = sum_k A[m,k]*B[n,k] (+bias), A/B f16,
// C fp32 or f16. 128x128 tile, BK=32, global_load_lds width=16.
// ---------------------------------------------------------------------------
__global__ __launch_bounds__(256) void gemm_f16(
    const f16* __restrict__ A, int lda, const f16* __restrict__ B, int ldb,
    const float* __restrict__ bias, void* __restrict__ Cv, int ldc, int K,
    int c_f16) {
  __shared__ f16 As[128 * 32];
  __shared__ f16 Bs[128 * 32];
  const int tid = threadIdx.x;
  const int lane = tid & 63, wave = tid >> 6;
  const int m0 = blockIdx.y << 7, n0 = blockIdx.x << 7;
  const int c0 = wave * 128 + lane, c1 = c0 + 64;
  const int r0 = c0 >> 2, s0 = c0 & 3;
  const int r1 = c1 >> 2, s1 = c1 & 3;
  const f16* Ab = A + (size_t)m0 * lda;
  const f16* Bb = B + (size_t)n0 * ldb;
  const int fm = lane & 15, fq = lane >> 4, fk = fq << 3;
  const int wm = (wave >> 1) << 6, wn = (wave & 1) << 6;
  f32x4 acc[4][4] = {};
  for (int k0 = 0; k0 < K; k0 += 32) {
    __syncthreads();
    glds16(Ab + (size_t)r0 * lda + k0 + s0 * 8, As + (size_t)c0 * 8 - lane * 8);
    glds16(Ab + (size_t)r1 * lda + k0 + s1 * 8, As + (size_t)c1 * 8 - lane * 8);
    glds16(Bb + (size_t)r0 * ldb + k0 + s0 * 8, Bs + (size_t)c0 * 8 - lane * 8);
    glds16(Bb + (size_t)r1 * ldb + k0 + s1 * 8, Bs + (size_t)c1 * 8 - lane * 8);
    __syncthreads();
    f16x8 af[4], bf[4];
#pragma unroll
    for (int mi = 0; mi < 4; mi++)
      af[mi] = *(const f16x8*)&As[(wm + mi * 16 + fm) * 32 + fk];
#pragma unroll
    for (int nj = 0; nj < 4; nj++)
      bf[nj] = *(const f16x8*)&Bs[(wn + nj * 16 + fm) * 32 + fk];
#pragma unroll
    for (int mi = 0; mi < 4; mi++)
#pragma unroll
      for (int nj = 0; nj < 4; nj++)
        acc[mi][nj] = __builtin_amdgcn_mfma_f32_16x16x32_f16(
            af[mi], bf[nj], acc[mi][nj], 0, 0, 0);
  }
  if (c_f16) {
    f16* C = (f16*)Cv;
#pragma unroll
    for (int mi = 0; mi < 4; mi++)
#pragma unroll
      for (int r = 0; r < 4; r++) {
        int row = m0 + wm + mi * 16 + fq * 4 + r;
        f16* cp = C + (size_t)row * ldc + n0 + wn + fm;
#pragma unroll
        for (int nj = 0; nj < 4; nj++) cp[nj * 16] = (f16)acc[mi][nj][r];
      }
  } else {
    float* C = (float*)Cv;
    float bb[4];
#pragma unroll
    for (int nj = 0; nj < 4; nj++)
      bb[nj] = bias ? bias[n0 + wn + nj * 16 + fm] : 0.f;
#pragma unroll
    for (int mi = 0; mi < 4; mi++)
#pragma unroll
      for (int r = 0; r < 4; r++) {
        int row = m0 + wm + mi * 16 + fq * 4 + r;
        float* cp = C + (size_t)row * ldc + n0 + wn + fm;
#pragma unroll
        for (int nj = 0; nj < 4; nj++) cp[nj * 16] = acc[mi][nj][r] + bb[nj];
      }
  }
}

// ---------------------------------------------------------------------------
// Fused dots + stage-1 top-32. blockIdx.x = z = h*2+p (fastest, Q reuse),
// blockIdx.y = m-tile. Wave computes 16 rows x 256 cols; selection via DPP
// row-max + swizzle broadcast; key low byte = (slot<<4)|lane (self-owning).
// ---------------------------------------------------------------------------
__global__ __launch_bounds__(256) void dots_topk1(
    const f16* __restrict__ Q,      // (4096, 2048)
    const f16* __restrict__ keysf,  // (8,256,2,128)
    float* __restrict__ s1s, int* __restrict__ s1i) {
  __shared__ f16 As[64 * 32];
  __shared__ f16 Bs[256 * 32];
  const int tid = threadIdx.x;
  const int lane = tid & 63, wave = tid >> 6;
  const int z = blockIdx.x;  // h*2+p
  const int h = z >> 1, p = z & 1;
  const int m0 = blockIdx.y << 6;
  const f16* Aq = Q + (size_t)m0 * 2048 + p * 1024 + h * 128;
  const f16* Bk = keysf + ((size_t)h * 512 + p) * 128;  // row stride 256 f16
  const int cA = wave * 64 + lane;
  const int rA = cA >> 2, sA = cA & 3;
  const int fm = lane & 15, fq = lane >> 4, fk = fq << 3;
  f32x4 acc[16] = {};
  for (int k0 = 0; k0 < 128; k0 += 32) {
    __syncthreads();
    glds16(Aq + (size_t)rA * 2048 + k0 + sA * 8, As + (size_t)cA * 8 - lane * 8);
#pragma unroll
    for (int c = 0; c < 4; c++) {
      int cB = (wave * 4 + c) * 64 + lane;
      int rB = cB >> 2, sB = cB & 3;
      glds16(Bk + (size_t)rB * 256 + k0 + sB * 8,
             Bs + (size_t)cB * 8 - lane * 8);
    }
    __syncthreads();
    f16x8 af = *(const f16x8*)&As[(wave * 16 + fm) * 32 + fk];
#pragma unroll
    for (int j = 0; j < 16; j++) {
      f16x8 bf = *(const f16x8*)&Bs[(j * 16 + fm) * 32 + fk];
      acc[j] = __builtin_amdgcn_mfma_f32_16x16x32_f16(af, bf, acc[j], 0, 0, 0);
    }
  }
  // top-32 per row; quad fq handles rows m0 + wave*16 + fq*4 + r.
  // score row element n = j*16 + fm lives in acc[j][r] of lane (fq*16+fm).
  for (int r = 0; r < 4; r++) {
    u32 key[16];
#pragma unroll
    for (int j = 0; j < 16; j++)
      key[j] = (f2sort(acc[j][r]) & ~0xFFu) | (u32)((j << 4) | fm);
    u32 g0 = 0, g1 = 0;
    for (int it = 0; it < 32; it++) {
      u32 lm = key[0];
#pragma unroll
      for (int j = 1; j < 16; j++) lm = key[j] > lm ? key[j] : lm;
      u32 gm = dppmax16(lm);
#pragma unroll
      for (int j = 0; j < 16; j++) key[j] = (key[j] == gm) ? 0u : key[j];
      bool sel = (fm == (it & 15));
      if (it < 16) g0 = sel ? gm : g0;
      else         g1 = sel ? gm : g1;
    }
    int m = m0 + wave * 16 + (fq << 2) + r;
    int b = m >> 11, t = m & 2047;
    size_t orow = ((((size_t)(b * 8 + h)) * TSEQ + t) * 2 + p) * 32;
    s1s[orow + fm] = sort2f(g0 & ~0xFFu);
    s1s[orow + fm + 16] = sort2f(g1 & ~0xFFu);
    s1i[orow + fm] = (int)(g0 & 0xFFu);       // n = (slot<<4)|lane
    s1i[orow + fm + 16] = (int)(g1 & 0xFFu);
  }
}

// ---------------------------------------------------------------------------
// Stage-2: combine halves, top-32 of 32x32 sum grid via dominance frontier
// ((i+1)(j+1)<=32 -> 119 candidates), DPP selection, softmax, f16 value
// gather (table is L3-resident at 128 MB), weighted sum -> f16 headout.
// ---------------------------------------------------------------------------
__global__ __launch_bounds__(256) void topk2_gather(
    const float* __restrict__ s1s, const int* __restrict__ s1i,
    const f16* __restrict__ valf, f16* __restrict__ headout) {
  __shared__ unsigned short cand[128];  // (i<<5)|j, 0xFFFF = pad
  __shared__ float s0sh[16][32];
  __shared__ float s1sh[16][32];
  __shared__ int i0sh[16][32];
  __shared__ int i1sh[16][32];
  __shared__ int vtab[16][32];
  __shared__ float wtab[16][32];
  const int tid = threadIdx.x;
  if (tid < 128) {
    int c = tid;
    unsigned short enc = 0xFFFF;
    if (c < 119) {
      int rem = c, i = 0;
      for (i = 0; i < 32; i++) {
        int cnt = 32 / (i + 1);
        if (rem < cnt) break;
        rem -= cnt;
      }
      enc = (unsigned short)((i << 5) | rem);
    }
    cand[tid] = enc;
  }
  const int rloc = tid >> 4;
  const int l = tid & 15;
  const int row = blockIdx.x * 16 + rloc;  // (b,h,t)
  const int b = row >> 14;
  const int h = (row >> 11) & 7;
  const int t = row & 2047;
  const int tt = t >> 1, p = t & 1;
  size_t rbase = (size_t)(b * 8 + h) * TSEQ;
  size_t base0 = ((rbase + tt) * 2 + p) * 32;
  size_t base1 = ((rbase + tt + 1024) * 2 + p) * 32;
  s0sh[rloc][l] = s1s[base0 + l];
  s0sh[rloc][l + 16] = s1s[base0 + l + 16];
  s1sh[rloc][l] = s1s[base1 + l];
  s1sh[rloc][l + 16] = s1s[base1 + l + 16];
  i0sh[rloc][l] = s1i[base0 + l];
  i0sh[rloc][l + 16] = s1i[base0 + l + 16];
  i1sh[rloc][l] = s1i[base1 + l];
  i1sh[rloc][l + 16] = s1i[base1 + l + 16];
  __syncthreads();
  u32 key[8];
#pragma unroll
  for (int s = 0; s < 8; s++) {
    int c = l + 16 * s;  // == (s<<4)|l
    unsigned short e = cand[c];
    u32 kk = 0u;
    if (e != 0xFFFF) {
      float v = s0sh[rloc][e >> 5] + s1sh[rloc][e & 31];
      kk = (f2sort(v) & ~0xFFu) | (u32)c;
    }
    key[s] = kk;
  }
  u32 g0 = 0, g1 = 0;
  for (int it = 0; it < 32; it++) {
    u32 lm = key[0];
#pragma unroll
    for (int s = 1; s < 8; s++) lm = key[s] > lm ? key[s] : lm;
    u32 gm = dppmax16(lm);
#pragma unroll
    for (int s = 0; s < 8; s++) key[s] = (key[s] == gm) ? 0u : key[s];
    bool sel = (l == (it & 15));
    if (it < 16) g0 = sel ? gm : g0;
    else         g1 = sel ? gm : g1;
  }
  // decode winners (lane l holds winners l and l+16, descending order)
  float sc0 = sort2f(g0 & ~0xFFu);
  float sc1 = sort2f(g1 & ~0xFFu);
  unsigned short e0c = cand[g0 & 0xFFu];
  unsigned short e1c = cand[g1 & 0xFFu];
  int vidx0 = i0sh[rloc][e0c >> 5] * 256 + i1sh[rloc][e0c & 31];
  int vidx1 = i0sh[rloc][e1c >> 5] * 256 + i1sh[rloc][e1c & 31];
  // softmax: winner 0 (group lane 0) is the max
  float mx = __int_as_float(
      __builtin_amdgcn_ds_swizzle(__float_as_int(sc0), 0x010));
  float e0 = __expf(sc0 - mx);
  float e1 = __expf(sc1 - mx);
  float inv = 1.0f / dppsum16(e0 + e1);
  vtab[rloc][l] = vidx0;
  vtab[rloc][l + 16] = vidx1;
  wtab[rloc][l] = e0 * inv;
  wtab[rloc][l + 16] = e1 * inv;
  // gather: 128 f16 per value row; lane reads 8 (16 B) -> 256 B/row-group
  const f16* vb = valf + (((size_t)h) << 16) * 128 + l * 8;
  float accf[8] = {};
#pragma unroll 8
  for (int k = 0; k < 32; k++) {
    int vi = vtab[rloc][k];      // LDS broadcast (same wave, no barrier)
    float wk = wtab[rloc][k];
    f16x8 vv = *(const f16x8*)(vb + (size_t)vi * 128);
#pragma unroll
    for (int j = 0; j < 8; j++) accf[j] += wk * (float)vv[j];
  }
  f16x8 o;
#pragma unroll
  for (int j = 0; j < 8; j++) o[j] = (f16)accf[j];
  f16* op = headout + (size_t)(b * TSEQ + t) * 1024 + h * 128 + l * 8;
  *(f16x8*)op = o;
}

// ---------------------------------------------------------------------------
extern "C" void kernel_launch(void* const* d_in, const int* in_sizes, int n_in,
                              void* d_out, int out_size, void* d_ws,
                              size_t ws_size, hipStream_t stream) {
  const float* x    = (const float*)d_in[0];  // (2,2048,1024)
  const float* Wq   = (const float*)d_in[1];  // (2048,1024)
  const float* keys = (const float*)d_in[2];  // (8,256,2,128)
  const float* vals = (const float*)d_in[3];  // (8,65536,128)
  const float* Wo   = (const float*)d_in[4];  // (1024,1024)
  const float* bo   = (const float*)d_in[5];  // (1024,)
  float* out = (float*)d_out;                 // (2,2048,1024) fp32
  char* ws = (char*)d_ws;
  f16*   xf   = (f16*)(ws);                         // 8 MB
  f16*   wqf  = (f16*)(ws + (size_t)(8u << 20));    // 4 MB
  f16*   wof  = (f16*)(ws + (size_t)(12u << 20));   // 2 MB
  f16*   kyf  = (f16*)(ws + (size_t)(14u << 20));   // 1 MB
  f16*   Qf   = (f16*)(ws + (size_t)(16u << 20));   // 16 MB (4096x2048)
  float* s1s  = (float*)(ws + (size_t)(32u << 20)); // 8 MB
  int*   s1i  = (int*)(ws + (size_t)(40u << 20));   // 8 MB
  f16*   hof  = (f16*)(ws + (size_t)(48u << 20));   // 8 MB (4096x1024)
  f16*   valf = (f16*)(ws + (size_t)(64u << 20));   // 128 MB (8,65536,128)

  // 0) fp32 -> f16 for x, Wq, Wo, keys, values
  cvt_all<<<dim3(73216), 256, 0, stream>>>(x, Wq, Wo, keys, vals, xf, wqf, wof,
                                           kyf, valf);
  // 1) Q = x @ Wq^T  (M=4096,N=2048,K=1024), f16 out
  gemm_f16<<<dim3(16, 32), 256, 0, stream>>>(xf, 1024, wqf, 1024, nullptr, Qf,
                                             2048, 1024, 1);
  // 2) dots + stage-1 top-32 fused (per (h,p): M=4096,N=256,K=128)
  dots_topk1<<<dim3(16, 64), 256, 0, stream>>>(Qf, kyf, s1s, s1i);
  // 3) stage-2 top-32 + softmax + f16 gather -> headout f16
  topk2_gather<<<dim3(32768 / 16), 256, 0, stream>>>(s1s, s1i, valf, hof);
  // 4) out = headout @ Wo^T + bo  (M=4096,N=1024,K=1024), fp32 out
  gemm_f16<<<dim3(8, 32), 256, 0, stream>>>(hof, 1024, wof, 1024, bo, out,
                                            1024, 1024, 0);
}